// Round 2
// baseline (88.356 us; speedup 1.0000x reference)
//
#include <hip/hip_runtime.h>
#include <math.h>

#define NQ    13
#define DIM   8192
#define BLOCK 512
#define NGATE 26

// R14 = R13 resubmitted verbatim (R13 bench was a GPUAcquisitionTimeout; no data).
// R13 = R7 champion + two-batch pairing (one block simulates 2 rows).
//  Theory: R7 issues at ~6 cyc/instr vs 2 ideal (4.2k instrs/wave, 16 waves/CU,
//  ~42us kernel) -> ~65% issue stall from barrier-lockstep convoys with only
//  2 phase-locked blocks/CU. Pairing gives deterministic intra-wave A/B ILP,
//  halves barriers per batch, halves gate-broadcast LDS reads per batch.
//  LDS 4x32KB state = 132KB -> 1 block/CU; launch_bounds(512,2) -> 256 VGPR cap.
// Failed lines (do not retry): v2f/packed math (R8/R9 +9us), global gate
// buffer (R8), 2-pass remaps (R5 -8us), chained-DPP gates (R5/R11),
// 1024-thread blocks (R11 -4us), P0 elision via strided global load (R10).

// Bank-quad spreading swizzle: XOR addr[4:2] with addr[9:7]. Preserves
// addr[1:0] => b128 groups stay intact. Applied at every LDS access.
__device__ __forceinline__ int SW(int a) { return a ^ (((a >> 7) & 7) << 2); }

// ---- CNOT-chain permutation (GF(2)-linear), compile-time ----
struct PCols { int c[NQ]; };
constexpr PCols make_cols(int r) {
    PCols P{};
    for (int b = 0; b < NQ; ++b) {
        int cc = 1 << b;
        for (int cq = 0; cq < NQ; ++cq) {
            const int cb = 12 - cq;
            const int tb = 12 - ((cq + r) % NQ);
            cc ^= ((cc >> cb) & 1) << tb;
        }
        P.c[b] = cc;
    }
    return P;
}
constexpr PCols C1 = make_cols(1);   // layer 0 CNOTs (r=1)
constexpr int make_rm6() {           // row 6 of layer-1 (r=2) permutation matrix
    int m = 0;
    for (int b = 0; b < NQ; ++b) m |= ((make_cols(2).c[b] >> 6) & 1) << b;
    return m;
}
constexpr int RM6 = make_rm6();

// scatter combos for pass-3 reg bits: j0->i0, j1->i1, j2->i10, j3->i11
struct Combos { int k[16]; };
constexpr Combos make_combos() {
    Combos K{};
    for (int j = 0; j < 16; ++j)
        K.k[j] = ((j & 1) ? C1.c[0] : 0) ^ ((j & 2) ? C1.c[1] : 0)
               ^ ((j & 4) ? C1.c[10] : 0) ^ ((j & 8) ? C1.c[11] : 0);
    return K;
}
constexpr Combos KC = make_combos();

// per-j PauliZ sign parity for the final reduce (j bits -> i bits {0,1,10,11})
constexpr int make_sjw() {
    int wv = 0;
    for (int j = 0; j < 16; ++j) {
        const int jm = (j & 3) | (((j >> 2) & 3) << 10);
        wv |= (__builtin_popcount(jm & RM6) & 1) << j;
    }
    return wv;
}
constexpr int SJW = make_sjw();

// ---- float2 complex helpers ----
__device__ __forceinline__ float2 f2mul(float s, float2 a) {
    return make_float2(s * a.x, s * a.y);
}
__device__ __forceinline__ float2 f2fma(float s, float2 a, float2 b) {
    return make_float2(fmaf(s, a.x, b.x), fmaf(s, a.y, b.y));
}
__device__ __forceinline__ float2 fswap(float2 a) { return make_float2(-a.y, a.x); }

// gate matrix as two float4 broadcasts:
//   a = {u00r,u00i,u01r,u01i}, b = {u10r,u10i,u11r,u11i}
struct G8 { float4 a, b; };
__device__ __forceinline__ G8 ldg8(const float* gm, int gi) {
    G8 g;
    g.a = *(const float4*)&gm[gi * 8];
    g.b = *(const float4*)&gm[gi * 8 + 4];
    return g;
}

// Rot gate on 16-amp register subcube, pair bit = reg index bit P
template<int P>
__device__ __forceinline__ void rotp(float2* c, const G8 g) {
    #pragma unroll
    for (int m = 0; m < 8; ++m) {
        const int j0 = ((m >> P) << (P + 1)) | (m & ((1 << P) - 1));
        const int j1 = j0 | (1 << P);
        const float2 a0 = c[j0], a1 = c[j1];
        const float2 s0 = fswap(a0), s1 = fswap(a1);
        c[j0] = f2fma(g.a.w, s1, f2fma(g.a.z, a1, f2fma(g.a.y, s0, f2mul(g.a.x, a0))));
        c[j1] = f2fma(g.b.w, s1, f2fma(g.b.z, a1, f2fma(g.b.y, s0, f2mul(g.b.x, a0))));
    }
}

// DPP quad-perm lane exchange: 0xB1 -> lane^1, 0x4E -> lane^2
template<int CTRL>
__device__ __forceinline__ float dppx(float v) {
    return __int_as_float(
        __builtin_amdgcn_update_dpp(0, __float_as_int(v), CTRL, 0xf, 0xf, true));
}
template<int CTRL>
__device__ __forceinline__ void rotlane(float2* c, const G8 g, const bool hi) {
    const float Ar = hi ? g.b.z : g.a.x;
    const float Ai = hi ? g.b.w : g.a.y;
    const float Br = hi ? g.b.x : g.a.z;
    const float Bi = hi ? g.b.y : g.a.w;
    #pragma unroll
    for (int j = 0; j < 16; ++j) {
        const float2 p  = make_float2(dppx<CTRL>(c[j].x), dppx<CTRL>(c[j].y));
        const float2 so = fswap(c[j]), sp = fswap(p);
        c[j] = f2fma(Bi, sp, f2fma(Br, p, f2fma(Ai, so, f2mul(Ar, c[j]))));
    }
}

__device__ __forceinline__ void loadgrp(const float* re, const float* im, int a, float2* c) {
    const float4 r = *(const float4*)&re[a];
    const float4 i = *(const float4*)&im[a];
    c[0] = make_float2(r.x, i.x); c[1] = make_float2(r.y, i.y);
    c[2] = make_float2(r.z, i.z); c[3] = make_float2(r.w, i.w);
}
__device__ __forceinline__ void storegrp(float* re, float* im, int a, const float2* c) {
    *(float4*)&re[a] = make_float4(c[0].x, c[1].x, c[2].x, c[3].x);
    *(float4*)&im[a] = make_float4(c[0].y, c[1].y, c[2].y, c[3].y);
}

__global__ __launch_bounds__(BLOCK, 2) void qsim_kernel(
    const float* __restrict__ x,
    const float* __restrict__ w,
    float* __restrict__ out)
{
    __shared__ __align__(16) float reA[DIM];
    __shared__ __align__(16) float imA[DIM];
    __shared__ __align__(16) float reB[DIM];
    __shared__ __align__(16) float imB[DIM];
    __shared__ __align__(16) float gm[NGATE * 8];
    __shared__ float red_sA[8], red_sB[8], red_aA[8], red_aB[8];

    const int b = blockIdx.x;          // pair index: rows 2b and 2b+1
    const int t = threadIdx.x;

    // ---- gate matrices, 26 threads, once per block (shared by both rows) ----
    if (t < NGATE) {
        const float phi = w[t * 3 + 0], theta = w[t * 3 + 1], omega = w[t * 3 + 2];
        float co, si;  sincosf(0.5f * theta, &si, &co);
        float sps, cps, sds, cds;
        sincosf(0.5f * (phi + omega), &sps, &cps);
        sincosf(0.5f * (phi - omega), &sds, &cds);
        float* g = &gm[t * 8];
        g[0] =  cps * co;  g[1] = -sps * co;   // u00
        g[2] = -cds * si;  g[3] = -sds * si;   // u01
        g[4] =  cds * si;  g[5] = -sds * si;   // u10
        g[6] =  cps * co;  g[7] =  sps * co;   // u11
    }

    // ---- P0: coalesced global -> LDS (re only; state starts real), ss ----
    const float4* xA4 = (const float4*)(x + (size_t)(2 * b)     * DIM);
    const float4* xB4 = (const float4*)(x + (size_t)(2 * b + 1) * DIM);
    float ssA = 0.f, ssB = 0.f;
    #pragma unroll
    for (int k = 0; k < 4; ++k) {
        const int m = t + BLOCK * k;
        const int a = SW(4 * m);
        const float4 vA = xA4[m];
        const float4 vB = xB4[m];
        *(float4*)&reA[a] = vA;
        *(float4*)&reB[a] = vB;
        ssA += vA.x * vA.x + vA.y * vA.y + vA.z * vA.z + vA.w * vA.w;
        ssB += vB.x * vB.x + vB.y * vB.y + vB.z * vB.z + vB.w * vB.w;
    }
    #pragma unroll
    for (int off = 32; off > 0; off >>= 1) {
        ssA += __shfl_down(ssA, off, 64);
        ssB += __shfl_down(ssB, off, 64);
    }
    if ((t & 63) == 0) { red_sA[t >> 6] = ssA; red_sB[t >> 6] = ssB; }
    __syncthreads();                      // B1: gm + re staging + red_s visible
    float totalA = 0.f, totalB = 0.f;
    #pragma unroll
    for (int i = 0; i < 8; ++i) { totalA += red_sA[i]; totalB += red_sB[i]; }

    float2 cA[16], cB[16];

    // Per-pass (t,j)->i mappings (identical to R7; all in-place, all b128):
    //  P1: i = t<<4 | j            reg i[3:0] (q12..q9), dpp i[5:4]=t[1:0] (q8,q7)
    //  P2: i[1:0]=j[1:0], i[7:6]=j[3:2], i[5:2]=t[5:2], i[9:8]=t[1:0], i[12:10]=t[8:6]
    //      reg gates i6,i7 (q6,q5), dpp i8,i9 (q4,q3)
    //  P3: i[1:0]=j[1:0], i[11:10]=j[3:2], i[9:2]=t[8:1], i12=t[0]
    //      reg gates i10,i11 (q2,q1), dpp i12 (q0)
    const int base2 = (((t >> 2) & 15) << 2) | ((t & 3) << 8) | (((t >> 6) & 7) << 10);
    const int base3 = (((t >> 1) & 255) << 2) | ((t & 1) << 12);

    #pragma unroll
    for (int l = 0; l < 2; ++l) {
        const int G = l * 13;

        // ---- pass 1: 6 gates (q12..q7) ----
        if (l == 0) {
            // im is identically zero at entry: load re only
            #pragma unroll
            for (int g = 0; g < 4; ++g) {
                const int a = SW((t << 4) | (g << 2));
                const float4 rA = *(const float4*)&reA[a];
                const float4 rB = *(const float4*)&reB[a];
                cA[4 * g + 0] = make_float2(rA.x, 0.f);
                cA[4 * g + 1] = make_float2(rA.y, 0.f);
                cA[4 * g + 2] = make_float2(rA.z, 0.f);
                cA[4 * g + 3] = make_float2(rA.w, 0.f);
                cB[4 * g + 0] = make_float2(rB.x, 0.f);
                cB[4 * g + 1] = make_float2(rB.y, 0.f);
                cB[4 * g + 2] = make_float2(rB.z, 0.f);
                cB[4 * g + 3] = make_float2(rB.w, 0.f);
            }
        } else {
            #pragma unroll
            for (int g = 0; g < 4; ++g) {
                const int a = SW((t << 4) | (g << 2));
                loadgrp(reA, imA, a, &cA[4 * g]);
                loadgrp(reB, imB, a, &cB[4 * g]);
            }
        }
        { const G8 gq = ldg8(gm, G + 12); rotp<0>(cA, gq); rotp<0>(cB, gq); }
        { const G8 gq = ldg8(gm, G + 11); rotp<1>(cA, gq); rotp<1>(cB, gq); }
        { const G8 gq = ldg8(gm, G + 10); rotp<2>(cA, gq); rotp<2>(cB, gq); }
        { const G8 gq = ldg8(gm, G +  9); rotp<3>(cA, gq); rotp<3>(cB, gq); }
        { const G8 gq = ldg8(gm, G + 8); const bool h = (t & 1) != 0;
          rotlane<0xB1>(cA, gq, h); rotlane<0xB1>(cB, gq, h); }
        { const G8 gq = ldg8(gm, G + 7); const bool h = (t & 2) != 0;
          rotlane<0x4E>(cA, gq, h); rotlane<0x4E>(cB, gq, h); }
        #pragma unroll
        for (int g = 0; g < 4; ++g) {
            const int a = SW((t << 4) | (g << 2));
            storegrp(reA, imA, a, &cA[4 * g]);
            storegrp(reB, imB, a, &cB[4 * g]);
        }
        __syncthreads();

        // ---- pass 2: 4 gates (q6..q3) ----
        #pragma unroll
        for (int h = 0; h < 4; ++h) {
            const int a = SW(base2 | (h << 6));
            loadgrp(reA, imA, a, &cA[4 * h]);
            loadgrp(reB, imB, a, &cB[4 * h]);
        }
        { const G8 gq = ldg8(gm, G + 6); rotp<2>(cA, gq); rotp<2>(cB, gq); }
        { const G8 gq = ldg8(gm, G + 5); rotp<3>(cA, gq); rotp<3>(cB, gq); }
        { const G8 gq = ldg8(gm, G + 4); const bool h = (t & 1) != 0;
          rotlane<0xB1>(cA, gq, h); rotlane<0xB1>(cB, gq, h); }
        { const G8 gq = ldg8(gm, G + 3); const bool h = (t & 2) != 0;
          rotlane<0x4E>(cA, gq, h); rotlane<0x4E>(cB, gq, h); }
        #pragma unroll
        for (int h = 0; h < 4; ++h) {
            const int a = SW(base2 | (h << 6));
            storegrp(reA, imA, a, &cA[4 * h]);
            storegrp(reB, imB, a, &cB[4 * h]);
        }
        __syncthreads();

        // ---- pass 3: 3 gates (q2,q1,q0) ----
        #pragma unroll
        for (int h = 0; h < 4; ++h) {
            const int a = SW(base3 | (h << 10));
            loadgrp(reA, imA, a, &cA[4 * h]);
            loadgrp(reB, imB, a, &cB[4 * h]);
        }
        if (l == 0) __syncthreads();   // reads drained before scatter (layer 0 only)
        { const G8 gq = ldg8(gm, G + 2); rotp<2>(cA, gq); rotp<2>(cB, gq); }
        { const G8 gq = ldg8(gm, G + 1); rotp<3>(cA, gq); rotp<3>(cB, gq); }
        { const G8 gq = ldg8(gm, G + 0); const bool h = (t & 1) != 0;
          rotlane<0xB1>(cA, gq, h); rotlane<0xB1>(cB, gq, h); }

        if (l == 0) {
            // all 13 layer-0 CNOTs as one GF(2)-linear scatter (both rows)
            int mb = 0;
            if (t & 1) mb ^= C1.c[12];
            #pragma unroll
            for (int bb = 0; bb < 8; ++bb)
                if ((t >> (bb + 1)) & 1) mb ^= C1.c[2 + bb];
            #pragma unroll
            for (int j = 0; j < 16; ++j) {
                const int a = SW(mb ^ KC.k[j]);
                reA[a] = cA[j].x; imA[a] = cA[j].y;
                reB[a] = cB[j].x; imB[a] = cB[j].y;
            }
            __syncthreads();
        }
    }

    // ---- layer-1 CNOTs + PauliZ(q6) folded: sign = popc(i & RM6) & 1 ----
    const int sbase = __popc(base3 & RM6) & 1;   // base3 == thread's fixed i-bits
    float accA = 0.f, accB = 0.f;
    #pragma unroll
    for (int j = 0; j < 16; ++j) {
        const float pA = cA[j].x * cA[j].x + cA[j].y * cA[j].y;
        const float pB = cB[j].x * cB[j].x + cB[j].y * cB[j].y;
        const bool neg = (sbase ^ ((SJW >> j) & 1)) != 0;
        accA += neg ? -pA : pA;
        accB += neg ? -pB : pB;
    }
    #pragma unroll
    for (int off = 32; off > 0; off >>= 1) {
        accA += __shfl_down(accA, off, 64);
        accB += __shfl_down(accB, off, 64);
    }
    if ((t & 63) == 0) { red_aA[t >> 6] = accA; red_aB[t >> 6] = accB; }
    __syncthreads();
    if (t == 0) {
        float tA = 0.f, tB = 0.f;
        #pragma unroll
        for (int i = 0; i < 8; ++i) { tA += red_aA[i]; tB += red_aB[i]; }
        out[2 * b]     = tA / totalA;
        out[2 * b + 1] = tB / totalB;
    }
}

extern "C" void kernel_launch(void* const* d_in, const int* in_sizes, int n_in,
                              void* d_out, int out_size, void* d_ws, size_t ws_size,
                              hipStream_t stream) {
    const float* x = (const float*)d_in[0];   // (512, 8192) fp32
    const float* w = (const float*)d_in[1];   // (2, 13, 3) fp32
    float* out = (float*)d_out;               // (512,) fp32
    const int B = in_sizes[0] / DIM;
    qsim_kernel<<<B / 2, BLOCK, 0, stream>>>(x, w, out);
}

// Round 5
// 86.628 us; speedup vs baseline: 1.0199x; 1.0199x over previous
//
#include <hip/hip_runtime.h>
#include <math.h>

#define NQ    13
#define DIM   8192
#define BLOCK 512
#define NGATE 26

// R17 = R15 resubmitted verbatim (R15/R16 benches were GPUAcquisitionTimeouts;
// the pipelining change has never been measured).
// R15 = R7 champion restored (512 blocks, 1 row/block, 2 blocks/CU) + load-use
// software pipelining inside each pass:
//   - pass gate matrices (broadcast b128) hoisted BEFORE state loads
//   - P1: bit0/bit1 gates applied per-4-amp-group right after all loads issue
//     (group g only needs its own 2 b128 -> compiler emits partial lgkmcnt)
//   - P2/P3: rotp<2> split into group-pair halves (first half needs groups 0,1)
// All reorders commute (single-qubit gates on distinct qubits); arithmetic
// per amplitude is bit-identical to R7.
// Failed lines (do not retry): v2f/packed math (R8/R9 +9us), global gate
// buffer (R8), 2-pass remaps (R5 -8us), chained-DPP gates (R5/R11),
// 1024-thread blocks (R11 -4us), P0 elision via strided global load (R10),
// two-batch pairing @1 block/CU (R13/R14 +3.4us: lost cross-block barrier
// overlap; intra-wave A/B ILP did not compensate).

// Bank-quad spreading swizzle: XOR addr[4:2] with addr[9:7]. Preserves
// addr[1:0] => b128 groups stay intact. Applied at every LDS access.
__device__ __forceinline__ int SW(int a) { return a ^ (((a >> 7) & 7) << 2); }

// ---- CNOT-chain permutation (GF(2)-linear), compile-time ----
struct PCols { int c[NQ]; };
constexpr PCols make_cols(int r) {
    PCols P{};
    for (int b = 0; b < NQ; ++b) {
        int cc = 1 << b;
        for (int cq = 0; cq < NQ; ++cq) {
            const int cb = 12 - cq;
            const int tb = 12 - ((cq + r) % NQ);
            cc ^= ((cc >> cb) & 1) << tb;
        }
        P.c[b] = cc;
    }
    return P;
}
constexpr PCols C1 = make_cols(1);   // layer 0 CNOTs (r=1)
constexpr int make_rm6() {           // row 6 of layer-1 (r=2) permutation matrix
    int m = 0;
    for (int b = 0; b < NQ; ++b) m |= ((make_cols(2).c[b] >> 6) & 1) << b;
    return m;
}
constexpr int RM6 = make_rm6();

// scatter combos for pass-3 reg bits: j0->i0, j1->i1, j2->i10, j3->i11
struct Combos { int k[16]; };
constexpr Combos make_combos() {
    Combos K{};
    for (int j = 0; j < 16; ++j)
        K.k[j] = ((j & 1) ? C1.c[0] : 0) ^ ((j & 2) ? C1.c[1] : 0)
               ^ ((j & 4) ? C1.c[10] : 0) ^ ((j & 8) ? C1.c[11] : 0);
    return K;
}
constexpr Combos KC = make_combos();

// per-j PauliZ sign parity for the final reduce (j bits -> i bits {0,1,10,11})
constexpr int make_sjw() {
    int wv = 0;
    for (int j = 0; j < 16; ++j) {
        const int jm = (j & 3) | (((j >> 2) & 3) << 10);
        wv |= (__builtin_popcount(jm & RM6) & 1) << j;
    }
    return wv;
}
constexpr int SJW = make_sjw();

// ---- float2 complex helpers ----
__device__ __forceinline__ float2 f2mul(float s, float2 a) {
    return make_float2(s * a.x, s * a.y);
}
__device__ __forceinline__ float2 f2fma(float s, float2 a, float2 b) {
    return make_float2(fmaf(s, a.x, b.x), fmaf(s, a.y, b.y));
}
__device__ __forceinline__ float2 fswap(float2 a) { return make_float2(-a.y, a.x); }

// gate matrix as two float4 broadcasts:
//   a = {u00r,u00i,u01r,u01i}, b = {u10r,u10i,u11r,u11i}
struct G8 { float4 a, b; };
__device__ __forceinline__ G8 ldg8(const float* gm, int gi) {
    G8 g;
    g.a = *(const float4*)&gm[gi * 8];
    g.b = *(const float4*)&gm[gi * 8 + 4];
    return g;
}

// one Rot gate on an amplitude pair
__device__ __forceinline__ void rotpair(float2& a0, float2& a1, const G8 g) {
    const float2 s0 = fswap(a0), s1 = fswap(a1);
    const float2 n0 = f2fma(g.a.w, s1, f2fma(g.a.z, a1, f2fma(g.a.y, s0, f2mul(g.a.x, a0))));
    const float2 n1 = f2fma(g.b.w, s1, f2fma(g.b.z, a1, f2fma(g.b.y, s0, f2mul(g.b.x, a0))));
    a0 = n0; a1 = n1;
}

// bit0 + bit1 gates applied within one 4-amp group (self-contained in 1 b128 pair)
__device__ __forceinline__ void rot2q(float2* c4, const G8 g0, const G8 g1) {
    rotpair(c4[0], c4[1], g0); rotpair(c4[2], c4[3], g0);   // pair bit 0
    rotpair(c4[0], c4[2], g1); rotpair(c4[1], c4[3], g1);   // pair bit 1
}

// Rot gate on 16-amp register subcube, pair bit = reg index bit P, pairs [m0,m1)
template<int P>
__device__ __forceinline__ void rotp_range(float2* c, const G8 g, const int m0, const int m1) {
    #pragma unroll
    for (int m = m0; m < m1; ++m) {
        const int j0 = ((m >> P) << (P + 1)) | (m & ((1 << P) - 1));
        const int j1 = j0 | (1 << P);
        rotpair(c[j0], c[j1], g);
    }
}
template<int P>
__device__ __forceinline__ void rotp(float2* c, const G8 g) {
    rotp_range<P>(c, g, 0, 8);
}

// DPP quad-perm lane exchange: 0xB1 -> lane^1, 0x4E -> lane^2
template<int CTRL>
__device__ __forceinline__ float dppx(float v) {
    return __int_as_float(
        __builtin_amdgcn_update_dpp(0, __float_as_int(v), CTRL, 0xf, 0xf, true));
}
template<int CTRL>
__device__ __forceinline__ void rotlane(float2* c, const G8 g, const bool hi) {
    const float Ar = hi ? g.b.z : g.a.x;
    const float Ai = hi ? g.b.w : g.a.y;
    const float Br = hi ? g.b.x : g.a.z;
    const float Bi = hi ? g.b.y : g.a.w;
    #pragma unroll
    for (int j = 0; j < 16; ++j) {
        const float2 p  = make_float2(dppx<CTRL>(c[j].x), dppx<CTRL>(c[j].y));
        const float2 so = fswap(c[j]), sp = fswap(p);
        c[j] = f2fma(Bi, sp, f2fma(Br, p, f2fma(Ai, so, f2mul(Ar, c[j]))));
    }
}

__device__ __forceinline__ void loadgrp(const float* re, const float* im, int a, float2* c) {
    const float4 r = *(const float4*)&re[a];
    const float4 i = *(const float4*)&im[a];
    c[0] = make_float2(r.x, i.x); c[1] = make_float2(r.y, i.y);
    c[2] = make_float2(r.z, i.z); c[3] = make_float2(r.w, i.w);
}
__device__ __forceinline__ void storegrp(float* re, float* im, int a, const float2* c) {
    *(float4*)&re[a] = make_float4(c[0].x, c[1].x, c[2].x, c[3].x);
    *(float4*)&im[a] = make_float4(c[0].y, c[1].y, c[2].y, c[3].y);
}

__global__ __launch_bounds__(BLOCK, 4) void qsim_kernel(
    const float* __restrict__ x,
    const float* __restrict__ w,
    float* __restrict__ out)
{
    __shared__ __align__(16) float re[DIM];
    __shared__ __align__(16) float im[DIM];
    __shared__ __align__(16) float gm[NGATE * 8];
    __shared__ float red_ss[8], red_acc[8];

    const int b = blockIdx.x;
    const int t = threadIdx.x;

    // ---- gate matrices, 26 threads, once per block ----
    if (t < NGATE) {
        const float phi = w[t * 3 + 0], theta = w[t * 3 + 1], omega = w[t * 3 + 2];
        float co, si;  sincosf(0.5f * theta, &si, &co);
        float sps, cps, sds, cds;
        sincosf(0.5f * (phi + omega), &sps, &cps);
        sincosf(0.5f * (phi - omega), &sds, &cds);
        float* g = &gm[t * 8];
        g[0] =  cps * co;  g[1] = -sps * co;   // u00
        g[2] = -cds * si;  g[3] = -sds * si;   // u01
        g[4] =  cds * si;  g[5] = -sds * si;   // u10
        g[6] =  cps * co;  g[7] =  sps * co;   // u11
    }

    // ---- P0: coalesced global -> LDS (re only; state starts real), ss ----
    const float4* x4 = (const float4*)(x + (size_t)b * DIM);
    float ss = 0.f;
    #pragma unroll
    for (int k = 0; k < 4; ++k) {
        const int m = t + BLOCK * k;
        const int a = SW(4 * m);
        const float4 v = x4[m];
        *(float4*)&re[a] = v;
        ss += v.x * v.x + v.y * v.y + v.z * v.z + v.w * v.w;
    }
    #pragma unroll
    for (int off = 32; off > 0; off >>= 1) ss += __shfl_down(ss, off, 64);
    if ((t & 63) == 0) red_ss[t >> 6] = ss;
    __syncthreads();                      // B1: gm + re staging + red_ss visible
    float total = 0.f;
    #pragma unroll
    for (int i = 0; i < 8; ++i) total += red_ss[i];  // ||x||^2, invariant

    float2 c[16];

    // Per-pass (t,j)->i mappings (identical to R7; all in-place, all b128):
    //  P1: i = t<<4 | j            reg i[3:0] (q12..q9), dpp i[5:4]=t[1:0] (q8,q7)
    //  P2: i[1:0]=j[1:0], i[7:6]=j[3:2], i[5:2]=t[5:2], i[9:8]=t[1:0], i[12:10]=t[8:6]
    //      reg gates i6,i7 (q6,q5), dpp i8,i9 (q4,q3)
    //  P3: i[1:0]=j[1:0], i[11:10]=j[3:2], i[9:2]=t[8:1], i12=t[0]
    //      reg gates i10,i11 (q2,q1), dpp i12 (q0)
    const int base2 = (((t >> 2) & 15) << 2) | ((t & 3) << 8) | (((t >> 6) & 7) << 10);
    const int base3 = (((t >> 1) & 255) << 2) | ((t & 1) << 12);

    #pragma unroll
    for (int l = 0; l < 2; ++l) {
        const int G = l * 13;

        // ---- pass 1: 6 gates (q12..q7) ----
        // gate regs for the per-group gates first (broadcast reads, in queue early)
        const G8 gA = ldg8(gm, G + 12);
        const G8 gB = ldg8(gm, G + 11);
        if (l == 0) {
            // im is identically zero at entry: load re only
            #pragma unroll
            for (int g = 0; g < 4; ++g) {
                const float4 r = *(const float4*)&re[SW((t << 4) | (g << 2))];
                c[4 * g + 0] = make_float2(r.x, 0.f);
                c[4 * g + 1] = make_float2(r.y, 0.f);
                c[4 * g + 2] = make_float2(r.z, 0.f);
                c[4 * g + 3] = make_float2(r.w, 0.f);
            }
        } else {
            #pragma unroll
            for (int g = 0; g < 4; ++g)
                loadgrp(re, im, SW((t << 4) | (g << 2)), &c[4 * g]);
        }
        const G8 gC = ldg8(gm, G + 10);
        const G8 gD = ldg8(gm, G +  9);
        const G8 gE = ldg8(gm, G +  8);
        const G8 gF = ldg8(gm, G +  7);
        // group g only depends on its own loads -> partial lgkmcnt waits
        #pragma unroll
        for (int g = 0; g < 4; ++g) rot2q(&c[4 * g], gA, gB);
        rotp<2>(c, gC);
        rotp<3>(c, gD);
        rotlane<0xB1>(c, gE, (t & 1) != 0);
        rotlane<0x4E>(c, gF, (t & 2) != 0);
        #pragma unroll
        for (int g = 0; g < 4; ++g)
            storegrp(re, im, SW((t << 4) | (g << 2)), &c[4 * g]);
        __syncthreads();

        // ---- pass 2: 4 gates (q6..q3) ----
        const G8 h6 = ldg8(gm, G + 6);
        const G8 h5 = ldg8(gm, G + 5);
        #pragma unroll
        for (int h = 0; h < 4; ++h) loadgrp(re, im, SW(base2 | (h << 6)), &c[4 * h]);
        const G8 h4 = ldg8(gm, G + 4);
        const G8 h3 = ldg8(gm, G + 3);
        rotp_range<2>(c, h6, 0, 4);   // needs groups 0,1 only -> partial wait
        rotp_range<2>(c, h6, 4, 8);   // groups 2,3
        rotp<3>(c, h5);
        rotlane<0xB1>(c, h4, (t & 1) != 0);
        rotlane<0x4E>(c, h3, (t & 2) != 0);
        #pragma unroll
        for (int h = 0; h < 4; ++h) storegrp(re, im, SW(base2 | (h << 6)), &c[4 * h]);
        __syncthreads();

        // ---- pass 3: 3 gates (q2,q1,q0) ----
        const G8 k2 = ldg8(gm, G + 2);
        const G8 k1 = ldg8(gm, G + 1);
        #pragma unroll
        for (int h = 0; h < 4; ++h) loadgrp(re, im, SW(base3 | (h << 10)), &c[4 * h]);
        const G8 k0 = ldg8(gm, G + 0);
        if (l == 0) __syncthreads();   // reads drained before scatter (layer 0 only)
        rotp_range<2>(c, k2, 0, 4);
        rotp_range<2>(c, k2, 4, 8);
        rotp<3>(c, k1);
        rotlane<0xB1>(c, k0, (t & 1) != 0);

        if (l == 0) {
            // all 13 layer-0 CNOTs as one GF(2)-linear scatter
            int mb = 0;
            if (t & 1) mb ^= C1.c[12];
            #pragma unroll
            for (int bb = 0; bb < 8; ++bb)
                if ((t >> (bb + 1)) & 1) mb ^= C1.c[2 + bb];
            #pragma unroll
            for (int j = 0; j < 16; ++j) {
                const int a = SW(mb ^ KC.k[j]);
                re[a] = c[j].x; im[a] = c[j].y;
            }
            __syncthreads();
        }
    }

    // ---- layer-1 CNOTs + PauliZ(q6) folded: sign = popc(i & RM6) & 1 ----
    const int sbase = __popc(base3 & RM6) & 1;   // base3 == thread's fixed i-bits
    float acc = 0.f;
    #pragma unroll
    for (int j = 0; j < 16; ++j) {
        const float p = c[j].x * c[j].x + c[j].y * c[j].y;
        acc += (sbase ^ ((SJW >> j) & 1)) ? -p : p;
    }
    #pragma unroll
    for (int off = 32; off > 0; off >>= 1) acc += __shfl_down(acc, off, 64);
    if ((t & 63) == 0) red_acc[t >> 6] = acc;
    __syncthreads();
    if (t == 0) {
        float tot = 0.f;
        #pragma unroll
        for (int i = 0; i < 8; ++i) tot += red_acc[i];
        out[b] = tot / total;
    }
}

extern "C" void kernel_launch(void* const* d_in, const int* in_sizes, int n_in,
                              void* d_out, int out_size, void* d_ws, size_t ws_size,
                              hipStream_t stream) {
    const float* x = (const float*)d_in[0];   // (512, 8192) fp32
    const float* w = (const float*)d_in[1];   // (2, 13, 3) fp32
    float* out = (float*)d_out;               // (512,) fp32
    const int B = in_sizes[0] / DIM;
    qsim_kernel<<<B, BLOCK, 0, stream>>>(x, w, out);
}

// Round 8
// 84.548 us; speedup vs baseline: 1.0450x; 1.0246x over previous
//
#include <hip/hip_runtime.h>
#include <math.h>

#define NQ    13
#define DIM   8192
#define BLOCK 512
#define NGATE 26

// R20 = R18 resubmitted verbatim (R18/R19 benches were GPUAcquisitionTimeouts;
// the barrier-elision change has never been measured).
// R18 = R7 champion body + wave-local barrier elision.
//  Dataflow proof: P1 writes i=t<<4|j  => wave w=t[8:6] owns {i : i[12:10]=w}.
//  P2 loads/stores i[12:10]=t[8:6]     => P1->P2 exchange is WAVE-LOCAL (both
//  layers). The __syncthreads there is replaced by a per-wave
//  s_waitcnt lgkmcnt(0) fence (asm, memory clobber). P2->P3 (i[9:2]=t[8:1],
//  cross-wave), P0->P1 (staging writer wave = i[10:8]), and scatter barriers
//  are genuinely cross-wave and kept. 2 of 7 block barriers removed; waves
//  de-phase between P1 and P3 -> better LDS/VALU overlap (the R13 lesson:
//  phase drift is the latency-hiding mechanism here).
// Failed/neutral lines (do not retry): v2f/packed math (R8/R9 +9us; gfx950
// fp32 peak 157TF == scalar full rate, pk gives no throughput), global gate
// buffer (R8), 2-pass remaps (R5), chained-DPP gates (R5/R11), 1024-thread
// blocks (R11), P0 elision via strided global load (R10), two-batch pairing
// @1 block/CU (R13/R14 +3.4us), load-use pipelining/gate-hoist (R15/R17
// neutral: compiler already emits partial lgkmcnt).

// Bank-quad spreading swizzle: XOR addr[4:2] with addr[9:7]. Preserves
// addr[1:0] => b128 groups stay intact. Applied at every LDS access.
__device__ __forceinline__ int SW(int a) { return a ^ (((a >> 7) & 7) << 2); }

// Per-wave LDS fence: all our ds_writes retired -> visible to all lanes of
// this wave. Replaces __syncthreads for wave-local producer/consumer passes.
__device__ __forceinline__ void wave_lds_fence() {
    asm volatile("s_waitcnt lgkmcnt(0)" ::: "memory");
}

// ---- CNOT-chain permutation (GF(2)-linear), compile-time ----
struct PCols { int c[NQ]; };
constexpr PCols make_cols(int r) {
    PCols P{};
    for (int b = 0; b < NQ; ++b) {
        int cc = 1 << b;
        for (int cq = 0; cq < NQ; ++cq) {
            const int cb = 12 - cq;
            const int tb = 12 - ((cq + r) % NQ);
            cc ^= ((cc >> cb) & 1) << tb;
        }
        P.c[b] = cc;
    }
    return P;
}
constexpr PCols C1 = make_cols(1);   // layer 0 CNOTs (r=1)
constexpr int make_rm6() {           // row 6 of layer-1 (r=2) permutation matrix
    int m = 0;
    for (int b = 0; b < NQ; ++b) m |= ((make_cols(2).c[b] >> 6) & 1) << b;
    return m;
}
constexpr int RM6 = make_rm6();

// scatter combos for pass-3 reg bits: j0->i0, j1->i1, j2->i10, j3->i11
struct Combos { int k[16]; };
constexpr Combos make_combos() {
    Combos K{};
    for (int j = 0; j < 16; ++j)
        K.k[j] = ((j & 1) ? C1.c[0] : 0) ^ ((j & 2) ? C1.c[1] : 0)
               ^ ((j & 4) ? C1.c[10] : 0) ^ ((j & 8) ? C1.c[11] : 0);
    return K;
}
constexpr Combos KC = make_combos();

// per-j PauliZ sign parity for the final reduce (j bits -> i bits {0,1,10,11})
constexpr int make_sjw() {
    int wv = 0;
    for (int j = 0; j < 16; ++j) {
        const int jm = (j & 3) | (((j >> 2) & 3) << 10);
        wv |= (__builtin_popcount(jm & RM6) & 1) << j;
    }
    return wv;
}
constexpr int SJW = make_sjw();

// ---- float2 complex helpers ----
__device__ __forceinline__ float2 f2mul(float s, float2 a) {
    return make_float2(s * a.x, s * a.y);
}
__device__ __forceinline__ float2 f2fma(float s, float2 a, float2 b) {
    return make_float2(fmaf(s, a.x, b.x), fmaf(s, a.y, b.y));
}
__device__ __forceinline__ float2 fswap(float2 a) { return make_float2(-a.y, a.x); }

// gate matrix as two float4 broadcasts:
//   a = {u00r,u00i,u01r,u01i}, b = {u10r,u10i,u11r,u11i}
struct G8 { float4 a, b; };
__device__ __forceinline__ G8 ldg8(const float* gm, int gi) {
    G8 g;
    g.a = *(const float4*)&gm[gi * 8];
    g.b = *(const float4*)&gm[gi * 8 + 4];
    return g;
}

// Rot gate on 16-amp register subcube, pair bit = reg index bit P
template<int P>
__device__ __forceinline__ void rotp(float2* c, const G8 g) {
    #pragma unroll
    for (int m = 0; m < 8; ++m) {
        const int j0 = ((m >> P) << (P + 1)) | (m & ((1 << P) - 1));
        const int j1 = j0 | (1 << P);
        const float2 a0 = c[j0], a1 = c[j1];
        const float2 s0 = fswap(a0), s1 = fswap(a1);
        c[j0] = f2fma(g.a.w, s1, f2fma(g.a.z, a1, f2fma(g.a.y, s0, f2mul(g.a.x, a0))));
        c[j1] = f2fma(g.b.w, s1, f2fma(g.b.z, a1, f2fma(g.b.y, s0, f2mul(g.b.x, a0))));
    }
}

// DPP quad-perm lane exchange: 0xB1 -> lane^1, 0x4E -> lane^2
template<int CTRL>
__device__ __forceinline__ float dppx(float v) {
    return __int_as_float(
        __builtin_amdgcn_update_dpp(0, __float_as_int(v), CTRL, 0xf, 0xf, true));
}
template<int CTRL>
__device__ __forceinline__ void rotlane(float2* c, const G8 g, const bool hi) {
    const float Ar = hi ? g.b.z : g.a.x;
    const float Ai = hi ? g.b.w : g.a.y;
    const float Br = hi ? g.b.x : g.a.z;
    const float Bi = hi ? g.b.y : g.a.w;
    #pragma unroll
    for (int j = 0; j < 16; ++j) {
        const float2 p  = make_float2(dppx<CTRL>(c[j].x), dppx<CTRL>(c[j].y));
        const float2 so = fswap(c[j]), sp = fswap(p);
        c[j] = f2fma(Bi, sp, f2fma(Br, p, f2fma(Ai, so, f2mul(Ar, c[j]))));
    }
}

__device__ __forceinline__ void loadgrp(const float* re, const float* im, int a, float2* c) {
    const float4 r = *(const float4*)&re[a];
    const float4 i = *(const float4*)&im[a];
    c[0] = make_float2(r.x, i.x); c[1] = make_float2(r.y, i.y);
    c[2] = make_float2(r.z, i.z); c[3] = make_float2(r.w, i.w);
}
__device__ __forceinline__ void storegrp(float* re, float* im, int a, const float2* c) {
    *(float4*)&re[a] = make_float4(c[0].x, c[1].x, c[2].x, c[3].x);
    *(float4*)&im[a] = make_float4(c[0].y, c[1].y, c[2].y, c[3].y);
}

__global__ __launch_bounds__(BLOCK, 4) void qsim_kernel(
    const float* __restrict__ x,
    const float* __restrict__ w,
    float* __restrict__ out)
{
    __shared__ __align__(16) float re[DIM];
    __shared__ __align__(16) float im[DIM];
    __shared__ __align__(16) float gm[NGATE * 8];
    __shared__ float red_ss[8], red_acc[8];

    const int b = blockIdx.x;
    const int t = threadIdx.x;

    // ---- gate matrices, 26 threads, once per block ----
    if (t < NGATE) {
        const float phi = w[t * 3 + 0], theta = w[t * 3 + 1], omega = w[t * 3 + 2];
        float co, si;  sincosf(0.5f * theta, &si, &co);
        float sps, cps, sds, cds;
        sincosf(0.5f * (phi + omega), &sps, &cps);
        sincosf(0.5f * (phi - omega), &sds, &cds);
        float* g = &gm[t * 8];
        g[0] =  cps * co;  g[1] = -sps * co;   // u00
        g[2] = -cds * si;  g[3] = -sds * si;   // u01
        g[4] =  cds * si;  g[5] = -sds * si;   // u10
        g[6] =  cps * co;  g[7] =  sps * co;   // u11
    }

    // ---- P0: coalesced global -> LDS (re only; state starts real), ss ----
    const float4* x4 = (const float4*)(x + (size_t)b * DIM);
    float ss = 0.f;
    #pragma unroll
    for (int k = 0; k < 4; ++k) {
        const int m = t + BLOCK * k;
        const int a = SW(4 * m);
        const float4 v = x4[m];
        *(float4*)&re[a] = v;
        ss += v.x * v.x + v.y * v.y + v.z * v.z + v.w * v.w;
    }
    #pragma unroll
    for (int off = 32; off > 0; off >>= 1) ss += __shfl_down(ss, off, 64);
    if ((t & 63) == 0) red_ss[t >> 6] = ss;
    __syncthreads();                      // B1: gm + re staging + red_ss (cross-wave)
    float total = 0.f;
    #pragma unroll
    for (int i = 0; i < 8; ++i) total += red_ss[i];  // ||x||^2, invariant

    float2 c[16];

    // Per-pass (t,j)->i mappings (identical to R7; all in-place, all b128):
    //  P1: i = t<<4 | j            reg i[3:0] (q12..q9), dpp i[5:4]=t[1:0] (q8,q7)
    //  P2: i[1:0]=j[1:0], i[7:6]=j[3:2], i[5:2]=t[5:2], i[9:8]=t[1:0], i[12:10]=t[8:6]
    //      reg gates i6,i7 (q6,q5), dpp i8,i9 (q4,q3)
    //  P3: i[1:0]=j[1:0], i[11:10]=j[3:2], i[9:2]=t[8:1], i12=t[0]
    //      reg gates i10,i11 (q2,q1), dpp i12 (q0)
    //  Wave-locality: P1 writes {i : i[12:10]=wave}; P2 reads/writes the same
    //  set -> P1->P2 needs only a per-wave lgkmcnt fence, no block barrier.
    const int base2 = (((t >> 2) & 15) << 2) | ((t & 3) << 8) | (((t >> 6) & 7) << 10);
    const int base3 = (((t >> 1) & 255) << 2) | ((t & 1) << 12);

    #pragma unroll
    for (int l = 0; l < 2; ++l) {
        const int G = l * 13;

        // ---- pass 1: 6 gates (q12..q7) ----
        if (l == 0) {
            // im is identically zero at entry: load re only
            #pragma unroll
            for (int g = 0; g < 4; ++g) {
                const float4 r = *(const float4*)&re[SW((t << 4) | (g << 2))];
                c[4 * g + 0] = make_float2(r.x, 0.f);
                c[4 * g + 1] = make_float2(r.y, 0.f);
                c[4 * g + 2] = make_float2(r.z, 0.f);
                c[4 * g + 3] = make_float2(r.w, 0.f);
            }
        } else {
            #pragma unroll
            for (int g = 0; g < 4; ++g)
                loadgrp(re, im, SW((t << 4) | (g << 2)), &c[4 * g]);
        }
        rotp<0>(c, ldg8(gm, G + 12));
        rotp<1>(c, ldg8(gm, G + 11));
        rotp<2>(c, ldg8(gm, G + 10));
        rotp<3>(c, ldg8(gm, G +  9));
        rotlane<0xB1>(c, ldg8(gm, G + 8), (t & 1) != 0);
        rotlane<0x4E>(c, ldg8(gm, G + 7), (t & 2) != 0);
        #pragma unroll
        for (int g = 0; g < 4; ++g)
            storegrp(re, im, SW((t << 4) | (g << 2)), &c[4 * g]);
        wave_lds_fence();              // P1->P2 is wave-local: no block barrier

        // ---- pass 2: 4 gates (q6..q3) ----
        #pragma unroll
        for (int h = 0; h < 4; ++h) loadgrp(re, im, SW(base2 | (h << 6)), &c[4 * h]);
        rotp<2>(c, ldg8(gm, G + 6));
        rotp<3>(c, ldg8(gm, G + 5));
        rotlane<0xB1>(c, ldg8(gm, G + 4), (t & 1) != 0);
        rotlane<0x4E>(c, ldg8(gm, G + 3), (t & 2) != 0);
        #pragma unroll
        for (int h = 0; h < 4; ++h) storegrp(re, im, SW(base2 | (h << 6)), &c[4 * h]);
        __syncthreads();               // P2->P3 reads i[9:2]=t[8:1]: cross-wave

        // ---- pass 3: 3 gates (q2,q1,q0) ----
        #pragma unroll
        for (int h = 0; h < 4; ++h) loadgrp(re, im, SW(base3 | (h << 10)), &c[4 * h]);
        if (l == 0) __syncthreads();   // reads drained before scatter (layer 0 only)
        rotp<2>(c, ldg8(gm, G + 2));
        rotp<3>(c, ldg8(gm, G + 1));
        rotlane<0xB1>(c, ldg8(gm, G + 0), (t & 1) != 0);

        if (l == 0) {
            // all 13 layer-0 CNOTs as one GF(2)-linear scatter
            int mb = 0;
            if (t & 1) mb ^= C1.c[12];
            #pragma unroll
            for (int bb = 0; bb < 8; ++bb)
                if ((t >> (bb + 1)) & 1) mb ^= C1.c[2 + bb];
            #pragma unroll
            for (int j = 0; j < 16; ++j) {
                const int a = SW(mb ^ KC.k[j]);
                re[a] = c[j].x; im[a] = c[j].y;
            }
            __syncthreads();           // scatter is cross-wave
        }
    }

    // ---- layer-1 CNOTs + PauliZ(q6) folded: sign = popc(i & RM6) & 1 ----
    const int sbase = __popc(base3 & RM6) & 1;   // base3 == thread's fixed i-bits
    float acc = 0.f;
    #pragma unroll
    for (int j = 0; j < 16; ++j) {
        const float p = c[j].x * c[j].x + c[j].y * c[j].y;
        acc += (sbase ^ ((SJW >> j) & 1)) ? -p : p;
    }
    #pragma unroll
    for (int off = 32; off > 0; off >>= 1) acc += __shfl_down(acc, off, 64);
    if ((t & 63) == 0) red_acc[t >> 6] = acc;
    __syncthreads();
    if (t == 0) {
        float tot = 0.f;
        #pragma unroll
        for (int i = 0; i < 8; ++i) tot += red_acc[i];
        out[b] = tot / total;
    }
}

extern "C" void kernel_launch(void* const* d_in, const int* in_sizes, int n_in,
                              void* d_out, int out_size, void* d_ws, size_t ws_size,
                              hipStream_t stream) {
    const float* x = (const float*)d_in[0];   // (512, 8192) fp32
    const float* w = (const float*)d_in[1];   // (2, 13, 3) fp32
    float* out = (float*)d_out;               // (512,) fp32
    const int B = in_sizes[0] / DIM;
    qsim_kernel<<<B, BLOCK, 0, stream>>>(x, w, out);
}